// Round 3
// baseline (333.819 us; speedup 1.0000x reference)
//
#include <hip/hip_runtime.h>

typedef unsigned short ushort_t;
typedef __bf16 bf16x8 __attribute__((ext_vector_type(8)));
typedef float f32x16 __attribute__((ext_vector_type(16)));
typedef float f32x4v __attribute__((ext_vector_type(4)));
typedef unsigned int u32x4 __attribute__((ext_vector_type(4)));
typedef unsigned int u32x2 __attribute__((ext_vector_type(2)));

#define L2E 1.44269504088896340736f

__device__ __forceinline__ unsigned cvt_pk_bf16(float a, float b) {
  unsigned r;
  asm("v_cvt_pk_bf16_f32 %0, %1, %2" : "=v"(r) : "v"(a), "v"(b));
  return r;
}

__device__ __forceinline__ float fast_exp2(float v) {
#if __has_builtin(__builtin_amdgcn_exp2f)
  return __builtin_amdgcn_exp2f(v);
#else
  return exp2f(v);
#endif
}

__device__ __forceinline__ float cross_half_max(float v) {
  return fmaxf(v, __shfl_xor(v, 32, 64));
}

__device__ __forceinline__ float cross_half_sum(float v) {
  return v + __shfl_xor(v, 32, 64);
}

__device__ __forceinline__ f32x16 mfma32(u32x4 a, u32x4 b, f32x16 c) {
  return __builtin_amdgcn_mfma_f32_32x32x16_bf16(
      __builtin_bit_cast(bf16x8, a), __builtin_bit_cast(bf16x8, b), c, 0, 0, 0);
}

// ---------------------------------------------------------------------------
// Projection: [320x256] W @ [256x4096] x -> Qt[b][n][32], Kt[b][m][32],
// V[b][c][m]  (all bf16).  grid 512 = 8 batches x 64 n-tiles(64).
// LDS: xT [64n][256c] bf16 swizzled (32KB) + W chunk [64o][256c] (32KB).
// 2 blocks/CU.
// ---------------------------------------------------------------------------
__global__ __launch_bounds__(256, 2) void proj_kernel(
    const float* __restrict__ x,
    const float* __restrict__ wq, const float* __restrict__ bq,
    const float* __restrict__ wk, const float* __restrict__ bk,
    const float* __restrict__ wv, const float* __restrict__ bv,
    ushort_t* __restrict__ qtg, ushort_t* __restrict__ ktg,
    ushort_t* __restrict__ vtg)
{
  __shared__ ushort_t xT[64 * 256];
  __shared__ ushort_t wl[64 * 256];

  const int tid  = threadIdx.x;
  const int b    = blockIdx.x & 7;     // batch -> XCD pin
  const int nt   = blockIdx.x >> 3;
  const int n0   = nt * 64;
  const int lane = tid & 63;
  const int wid  = tid >> 6;
  const int l31  = lane & 31;
  const int half = lane >> 5;
  const int nh   = wid & 1;            // n-half (32)
  const int oh   = wid >> 1;           // o-half (32)

  // ---- stage xT[n][c] (bf16, swizzled: byte ^= (n&7)<<4) ----
  {
    const int xn   = tid & 63;
    const int cgrp = tid >> 6;         // 4 groups of 64 channels
    const float* xb = x + (size_t)b * 256 * 4096 + (n0 + xn);
    #pragma unroll
    for (int j = 0; j < 8; ++j) {
      const int c0 = cgrp * 64 + j * 8;
      float f0 = xb[(size_t)(c0+0)*4096], f1 = xb[(size_t)(c0+1)*4096];
      float f2 = xb[(size_t)(c0+2)*4096], f3 = xb[(size_t)(c0+3)*4096];
      float f4 = xb[(size_t)(c0+4)*4096], f5 = xb[(size_t)(c0+5)*4096];
      float f6 = xb[(size_t)(c0+6)*4096], f7 = xb[(size_t)(c0+7)*4096];
      u32x4 pk;
      pk.x = cvt_pk_bf16(f0, f1); pk.y = cvt_pk_bf16(f2, f3);
      pk.z = cvt_pk_bf16(f4, f5); pk.w = cvt_pk_bf16(f6, f7);
      *(u32x4*)((char*)xT + xn*512 + ((c0*2) ^ ((xn & 7) << 4))) = pk;
    }
  }

  for (int oc = 0; oc < 5; ++oc) {
    __syncthreads();  // previous wl reads done (first: nothing)
    // ---- stage W chunk [oc*64, oc*64+64) as bf16, coalesced linear ----
    #pragma unroll
    for (int i = 0; i < 16; ++i) {
      const int lin4 = i * 256 + tid;        // f32x4 index
      const int row  = lin4 >> 6;            // 0..63
      const int c4   = (lin4 & 63) * 4;      // float col
      const int grow = oc * 64 + row;
      const float* wrow = (grow < 32) ? (wq + grow*256)
                        : (grow < 64) ? (wk + (grow-32)*256)
                                      : (wv + (grow-64)*256);
      f32x4v g = *(const f32x4v*)(wrow + c4);
      u32x2 pk2; pk2.x = cvt_pk_bf16(g.x, g.y); pk2.y = cvt_pk_bf16(g.z, g.w);
      *(u32x2*)((char*)wl + row*512 + ((c4*2) ^ ((row & 7) << 4))) = pk2;
    }
    __syncthreads();

    // ---- per-wave: 32 n-cols x 32 o-rows, K = 256 ----
    f32x16 acc = {};
    const int nloc = nh*32 + l31;
    const int oloc = oh*32 + l31;
    #pragma unroll
    for (int kc = 0; kc < 16; ++kc) {
      const int cb = kc*16 + half*8;
      u32x4 bf = *(const u32x4*)((const char*)xT + nloc*512 + ((cb*2) ^ ((nloc & 7) << 4)));
      u32x4 af = *(const u32x4*)((const char*)wl + oloc*512 + ((cb*2) ^ ((oloc & 7) << 4)));
      acc = mfma32(af, bf, acc);
    }

    const int nglob = n0 + nh*32 + l31;
    if (oc == 0) {
      // oh==0 -> Q rows 0..31, oh==1 -> K rows 0..31 ; store [n][o] bf16
      ushort_t* dst = oh ? ktg : qtg;
      const float* bias = oh ? bk : bq;
      const size_t rowbase = ((size_t)b*4096 + nglob) * 32;
      #pragma unroll
      for (int g = 0; g < 4; ++g) {
        const int ob = 8*g + 4*half;          // D row = (r&3)+8*(r>>2)+4*half
        float v0 = acc[4*g+0] + bias[ob+0];
        float v1 = acc[4*g+1] + bias[ob+1];
        float v2 = acc[4*g+2] + bias[ob+2];
        float v3 = acc[4*g+3] + bias[ob+3];
        u32x2 pk2; pk2.x = cvt_pk_bf16(v0, v1); pk2.y = cvt_pk_bf16(v2, v3);
        *(u32x2*)(dst + rowbase + ob) = pk2;
      }
    } else {
      const int cbase = (oc-1)*64 + oh*32;    // V channel base
      #pragma unroll
      for (int r = 0; r < 16; ++r) {
        const int c = cbase + (r & 3) + 8*(r >> 2) + 4*half;
        float v = acc[r] + bv[c];
        vtg[((size_t)b*256 + c)*4096 + nglob] = (ushort_t)cvt_pk_bf16(v, v);
      }
    }
  }
}

// ---------------------------------------------------------------------------
// Flash attention. grid 256 = 8 batches x 32 q-tiles(128); 512 thr = 8 waves
// = 2 q-groups(64q) x 4 c-groups(64c)  -> 2 waves/SIMD.
// LDS: V tiles in FRAGMENT ORDER (conflict-free lane-linear ds_read_b128),
// double-buffered 2x16KB; K tiles likewise 2x2KB. Staged via global_load_lds
// with per-lane permuted global source. Softmax in-register via swapped QK^T;
// cross-half exchange via __shfl_xor (proven round-1 construction).
// One vmcnt(0)+barrier per tile.
// ---------------------------------------------------------------------------
__global__ __launch_bounds__(512, 2) void attn_kernel(
    const ushort_t* __restrict__ qtg, const ushort_t* __restrict__ ktg,
    const ushort_t* __restrict__ vtg, const float* __restrict__ x,
    const float* __restrict__ gamma, float* __restrict__ out)
{
  __shared__ ushort_t vls[2 * 8192];   // 2 x 16KB V tile, fragment order
  __shared__ ushort_t kls[2 * 1024];   // 2 x  2KB K tile, fragment order

  const int tid  = threadIdx.x;
  const int lane = tid & 63;
  const int wid  = tid >> 6;           // 0..7
  const int l31  = lane & 31;
  const int half = lane >> 5;
  const int qg   = wid & 1;            // 64-query group
  const int ch   = wid >> 1;           // 64-channel group (0..3)
  const int b    = blockIdx.x & 7;     // batch -> XCD pin
  const int qt   = blockIdx.x >> 3;
  const int qbase = qt*128 + qg*64;

  const ushort_t* ktb = ktg + (size_t)b*4096*32;
  const ushort_t* vgb = vtg + (size_t)b*256*4096;

  // persistent Q B-fragments: q[qt2][ochunk]
  u32x4 qf[2][2];
  #pragma unroll
  for (int qt2 = 0; qt2 < 2; ++qt2) {
    const ushort_t* qrow = qtg + ((size_t)b*4096 + qbase + qt2*32 + l31)*32;
    qf[qt2][0] = *(const u32x4*)(qrow + half*8);
    qf[qt2][1] = *(const u32x4*)(qrow + 16 + half*8);
  }

  // ---- staging helpers (fragment-order; LDS dest wave-uniform) ----
  #define STAGE_TILE(nb, t) do {                                              \
    _Pragma("unroll")                                                         \
    for (int i = 0; i < 2; ++i) {                                             \
      const ushort_t* gp = vgb + (size_t)(wid*32 + l31)*4096 + (t)*32 + (i*2+half)*8; \
      const ushort_t* lp = vls + (nb)*8192 + wid*1024 + i*512;                \
      __builtin_amdgcn_global_load_lds(                                       \
          (const __attribute__((address_space(1))) void*)gp,                  \
          (__attribute__((address_space(3))) void*)lp, 16, 0, 0);             \
    }                                                                         \
    if (wid < 2) {                                                            \
      const ushort_t* gp = ktb + (size_t)((t)*32 + l31)*32 + wid*16 + half*8; \
      const ushort_t* lp = kls + (nb)*1024 + wid*512;                         \
      __builtin_amdgcn_global_load_lds(                                       \
          (const __attribute__((address_space(1))) void*)gp,                  \
          (__attribute__((address_space(3))) void*)lp, 16, 0, 0);             \
    }                                                                         \
  } while (0)

  // prologue: stage tile 0
  STAGE_TILE(0, 0);
  asm volatile("s_waitcnt vmcnt(0)" ::: "memory");
  __syncthreads();

  float mrun[2] = {-3.0e38f, -3.0e38f};
  float lrun[2] = {0.0f, 0.0f};
  f32x16 oacc[4] = {};                 // [qt2][ct]

  #pragma unroll 2
  for (int t = 0; t < 128; ++t) {
    const int cur = t & 1;

    // issue next-tile stage first (hidden under this tile's compute)
    if (t < 127) STAGE_TILE(cur ^ 1, t + 1);

    // K fragments (lane-linear contiguous)
    const char* kb = (const char*)kls + cur*2048;
    const u32x4 kf0 = *(const u32x4*)(kb + half*512 + l31*16);
    const u32x4 kf1 = *(const u32x4*)(kb + 1024 + half*512 + l31*16);

    // V fragments vf[ct][mh] (lane-linear contiguous)
    const char* vb = (const char*)vls + cur*16384;
    u32x4 vf[2][2];
    #pragma unroll
    for (int ct = 0; ct < 2; ++ct)
      #pragma unroll
      for (int mh = 0; mh < 2; ++mh)
        vf[ct][mh] = *(const u32x4*)(vb + (((ch*2+ct)*4 + mh*2 + half)*32 + l31)*16);

    // S^T = K . Q^T for both q-subtiles
    f32x16 s0 = {}, s1 = {};
    __builtin_amdgcn_s_setprio(1);
    s0 = mfma32(kf0, qf[0][0], s0);  s0 = mfma32(kf1, qf[0][1], s0);
    s1 = mfma32(kf0, qf[1][0], s1);  s1 = mfma32(kf1, qf[1][1], s1);
    __builtin_amdgcn_s_setprio(0);

    u32x4 pb[2][2];                    // [qt2][mh] PV B-fragments
    #pragma unroll
    for (int qt2 = 0; qt2 < 2; ++qt2) {
      const f32x16 s = qt2 ? s1 : s0;
      // row-max over 16 local + 16 partner m-values
      float x0 = fmaxf(fmaxf(s[0],  s[1]),  fmaxf(s[2],  s[3]));
      float x1 = fmaxf(fmaxf(s[4],  s[5]),  fmaxf(s[6],  s[7]));
      float x2 = fmaxf(fmaxf(s[8],  s[9]),  fmaxf(s[10], s[11]));
      float x3 = fmaxf(fmaxf(s[12], s[13]), fmaxf(s[14], s[15]));
      const float vmx  = fmaxf(fmaxf(x0, x1), fmaxf(x2, x3));
      const float pmax = cross_half_max(vmx);

      if (__any(pmax > mrun[qt2] + 8.0f)) {   // defer-max (T13)
        const float mnew = fmaxf(mrun[qt2], pmax);
        const float sc   = fast_exp2((mrun[qt2] - mnew) * L2E);
        lrun[qt2] *= sc;
        #pragma unroll
        for (int ct = 0; ct < 2; ++ct)
          #pragma unroll
          for (int r = 0; r < 16; ++r) oacc[qt2*2+ct][r] *= sc;
        mrun[qt2] = mnew;
      }

      const float ml2 = mrun[qt2] * L2E;
      float p[16];
      #pragma unroll
      for (int r = 0; r < 16; ++r) p[r] = fast_exp2(fmaf(s[r], L2E, -ml2));
      const float ps = (((p[0]+p[1])+(p[2]+p[3])) + ((p[4]+p[5])+(p[6]+p[7])))
                     + (((p[8]+p[9])+(p[10]+p[11])) + ((p[12]+p[13])+(p[14]+p[15])));
      lrun[qt2] += cross_half_sum(ps);

      // pack to bf16; build B-fragments via proven shfl_xor(32) exchange
      const unsigned wd0 = cvt_pk_bf16(p[0],  p[1]),  wd1 = cvt_pk_bf16(p[2],  p[3]);
      const unsigned wd2 = cvt_pk_bf16(p[4],  p[5]),  wd3 = cvt_pk_bf16(p[6],  p[7]);
      const unsigned wd4 = cvt_pk_bf16(p[8],  p[9]),  wd5 = cvt_pk_bf16(p[10], p[11]);
      const unsigned wd6 = cvt_pk_bf16(p[12], p[13]), wd7 = cvt_pk_bf16(p[14], p[15]);
      const unsigned pw0 = __shfl_xor((int)wd0, 32, 64), pw1 = __shfl_xor((int)wd1, 32, 64);
      const unsigned pw2 = __shfl_xor((int)wd2, 32, 64), pw3 = __shfl_xor((int)wd3, 32, 64);
      const unsigned pw4 = __shfl_xor((int)wd4, 32, 64), pw5 = __shfl_xor((int)wd5, 32, 64);
      const unsigned pw6 = __shfl_xor((int)wd6, 32, 64), pw7 = __shfl_xor((int)wd7, 32, 64);
      pb[qt2][0].x = half ? pw2 : wd0;  pb[qt2][0].y = half ? pw3 : wd1;
      pb[qt2][0].z = half ? wd2 : pw0;  pb[qt2][0].w = half ? wd3 : pw1;
      pb[qt2][1].x = half ? pw6 : wd4;  pb[qt2][1].y = half ? pw7 : wd5;
      pb[qt2][1].z = half ? wd6 : pw4;  pb[qt2][1].w = half ? wd7 : pw5;
    }

    // O[c][q] += V[c][m] P^T[m][q]
    __builtin_amdgcn_s_setprio(1);
    #pragma unroll
    for (int qt2 = 0; qt2 < 2; ++qt2)
      #pragma unroll
      for (int ct = 0; ct < 2; ++ct) {
        oacc[qt2*2+ct] = mfma32(vf[ct][0], pb[qt2][0], oacc[qt2*2+ct]);
        oacc[qt2*2+ct] = mfma32(vf[ct][1], pb[qt2][1], oacc[qt2*2+ct]);
      }
    __builtin_amdgcn_s_setprio(0);

    asm volatile("s_waitcnt vmcnt(0)" ::: "memory");
    __syncthreads();
  }

  // epilogue: out = x + gamma * O / l
  const float g = gamma[0];
  #pragma unroll
  for (int qt2 = 0; qt2 < 2; ++qt2) {
    const float inv_l = 1.0f / lrun[qt2];
    const size_t nglob = qbase + qt2*32 + l31;
    const float* xb = x   + (size_t)b*256*4096 + nglob;
    float*       ob = out + (size_t)b*256*4096 + nglob;
    #pragma unroll
    for (int ct = 0; ct < 2; ++ct) {
      #pragma unroll
      for (int r = 0; r < 16; ++r) {
        const int c = ch*64 + ct*32 + (r & 3) + 8*(r >> 2) + 4*half;
        const size_t off = (size_t)c * 4096;
        ob[off] = xb[off] + g * (oacc[qt2*2+ct][r] * inv_l);
      }
    }
  }
}

extern "C" void kernel_launch(void* const* d_in, const int* in_sizes, int n_in,
                              void* d_out, int out_size, void* d_ws, size_t ws_size,
                              hipStream_t stream) {
  (void)in_sizes; (void)n_in; (void)out_size; (void)ws_size;
  const float* x     = (const float*)d_in[0];
  const float* wq    = (const float*)d_in[1];
  const float* bq    = (const float*)d_in[2];
  const float* wk    = (const float*)d_in[3];
  const float* bk    = (const float*)d_in[4];
  const float* wv    = (const float*)d_in[5];
  const float* bv    = (const float*)d_in[6];
  const float* gamma = (const float*)d_in[7];
  float* out = (float*)d_out;

  ushort_t* ws  = (ushort_t*)d_ws;
  ushort_t* qtw = ws;                              // [8][4096][32] bf16
  ushort_t* ktw = ws + (size_t)8*4096*32;          // [8][4096][32] bf16
  ushort_t* vww = ws + (size_t)2*8*4096*32;        // [8][256][4096] bf16

  proj_kernel<<<512, 256, 0, stream>>>(x, wq, bq, wk, bk, wv, bv, qtw, ktw, vww);
  attn_kernel<<<256, 512, 0, stream>>>(qtw, ktw, vww, x, gamma, out);
}

// Round 4
// 228.746 us; speedup vs baseline: 1.4593x; 1.4593x over previous
//
#include <hip/hip_runtime.h>

typedef unsigned short ushort_t;
typedef __bf16 bf16x8 __attribute__((ext_vector_type(8)));
typedef float f32x16 __attribute__((ext_vector_type(16)));
typedef float f32x4v __attribute__((ext_vector_type(4)));
typedef unsigned int u32x4 __attribute__((ext_vector_type(4)));
typedef unsigned int u32x2 __attribute__((ext_vector_type(2)));

#define L2E 1.44269504088896340736f

__device__ __forceinline__ unsigned cvt_pk_bf16(float a, float b) {
  unsigned r;
  asm("v_cvt_pk_bf16_f32 %0, %1, %2" : "=v"(r) : "v"(a), "v"(b));
  return r;
}

__device__ __forceinline__ float fast_exp2(float v) {
#if __has_builtin(__builtin_amdgcn_exp2f)
  return __builtin_amdgcn_exp2f(v);
#else
  return exp2f(v);
#endif
}

__device__ __forceinline__ float cross_half_max(float v) {
  return fmaxf(v, __shfl_xor(v, 32, 64));
}

__device__ __forceinline__ float cross_half_sum(float v) {
  return v + __shfl_xor(v, 32, 64);
}

__device__ __forceinline__ f32x16 mfma32(u32x4 a, u32x4 b, f32x16 c) {
  return __builtin_amdgcn_mfma_f32_32x32x16_bf16(
      __builtin_bit_cast(bf16x8, a), __builtin_bit_cast(bf16x8, b), c, 0, 0, 0);
}

// ---------------------------------------------------------------------------
// Projection: [320x256] W @ [256x4096] x -> Qt[b][n][32], Kt[b][m][32],
// V[b][c][m] (bf16).  grid 1024 = 8 b x 128 n-tiles(32).  256 thr, 2 blk/CU.
// LDS fragment-order: xT 16KB (conflict-free rd+wr), wl 64KB (XOR swizzle).
// ---------------------------------------------------------------------------
__global__ __launch_bounds__(256, 2) void proj_kernel(
    const float* __restrict__ x,
    const float* __restrict__ wq, const float* __restrict__ bq,
    const float* __restrict__ wk, const float* __restrict__ bk,
    const float* __restrict__ wv, const float* __restrict__ bv,
    ushort_t* __restrict__ qtg, ushort_t* __restrict__ ktg,
    ushort_t* __restrict__ vtg)
{
  __shared__ ushort_t xT[1024 * 8];    // slot (cchunk*32+n): x[c0..c0+7][n] bf16
  __shared__ ushort_t wl[4096 * 8];    // slot (cchunk,row) swizzled

  const int tid  = threadIdx.x;
  const int b    = blockIdx.x & 7;     // batch -> XCD pin
  const int nt   = blockIdx.x >> 3;
  const int n0   = nt * 32;
  const int lane = tid & 63;
  const int wid  = tid >> 6;
  const int l31  = lane & 31;
  const int half = lane >> 5;

  // ---- stage xT: thread covers xn = tid&31, cchunks (tid>>5)*4 .. +3 ----
  {
    const int xn = tid & 31;
    const int cg = (tid >> 5) * 4;
    const float* xb = x + (size_t)b * 256 * 4096 + n0 + xn;
    float f[4][8];
    #pragma unroll
    for (int s = 0; s < 4; ++s) {
      const int c0 = (cg + s) * 8;
      #pragma unroll
      for (int k = 0; k < 8; ++k) f[s][k] = xb[(size_t)(c0 + k) * 4096];
    }
    #pragma unroll
    for (int s = 0; s < 4; ++s) {
      u32x4 pk;
      pk.x = cvt_pk_bf16(f[s][0], f[s][1]); pk.y = cvt_pk_bf16(f[s][2], f[s][3]);
      pk.z = cvt_pk_bf16(f[s][4], f[s][5]); pk.w = cvt_pk_bf16(f[s][6], f[s][7]);
      *(u32x4*)(xT + ((size_t)(cg + s) * 32 + xn) * 8) = pk;
    }
  }

  #pragma unroll
  for (int oc = 0; oc < 3; ++oc) {
    const int rows = (oc == 2) ? 64 : 128;
    __syncthreads();                   // prior wl reads done (covers xT on oc0)
    // ---- stage W rows [oc*128, oc*128+rows) ----
    for (int it = 0; it < rows / 8; ++it) {
      const int lin    = it * 256 + tid;
      const int row    = lin >> 5;
      const int cchunk = lin & 31;
      const int grow   = oc * 128 + row;
      const float* wrow = (grow < 32) ? (wq + grow * 256)
                        : (grow < 64) ? (wk + (grow - 32) * 256)
                                      : (wv + (grow - 64) * 256);
      f32x4v g0 = *(const f32x4v*)(wrow + cchunk * 8);
      f32x4v g1 = *(const f32x4v*)(wrow + cchunk * 8 + 4);
      u32x4 pk;
      pk.x = cvt_pk_bf16(g0.x, g0.y); pk.y = cvt_pk_bf16(g0.z, g0.w);
      pk.z = cvt_pk_bf16(g1.x, g1.y); pk.w = cvt_pk_bf16(g1.z, g1.w);
      *(u32x4*)((char*)wl + cchunk * 2048 + ((row * 16) ^ ((cchunk & 7) << 4))) = pk;
    }
    __syncthreads();

    const int og0 = oc * 128 + wid * 32;
    if (og0 < 320) {
      f32x16 acc = {};
      const int rloc = wid * 32 + l31;   // local W row
      #pragma unroll
      for (int kc = 0; kc < 16; ++kc) {
        const int cchunk = kc * 2 + half;
        u32x4 bf = *(const u32x4*)(xT + ((size_t)cchunk * 32 + l31) * 8);
        u32x4 af = *(const u32x4*)((const char*)wl + cchunk * 2048 +
                                   ((rloc * 16) ^ ((cchunk & 7) << 4)));
        acc = mfma32(af, bf, acc);
      }
      const int n = n0 + l31;
      if (og0 < 64) {
        // Q (og0==0) or K (og0==32); store [n][o] bf16
        ushort_t* dst = (og0 == 0) ? qtg : ktg;
        const float* bias = (og0 == 0) ? bq : bk;
        const size_t rowbase = ((size_t)b * 4096 + n) * 32;
        #pragma unroll
        for (int g = 0; g < 4; ++g) {
          const int ob = 8 * g + 4 * half;
          float v0 = acc[4*g+0] + bias[ob+0];
          float v1 = acc[4*g+1] + bias[ob+1];
          float v2 = acc[4*g+2] + bias[ob+2];
          float v3 = acc[4*g+3] + bias[ob+3];
          u32x2 pk2; pk2.x = cvt_pk_bf16(v0, v1); pk2.y = cvt_pk_bf16(v2, v3);
          *(u32x2*)(dst + rowbase + ob) = pk2;
        }
      } else {
        const int cbase = og0 - 64;
        #pragma unroll
        for (int r = 0; r < 16; ++r) {
          const int c = cbase + (r & 3) + 8 * (r >> 2) + 4 * half;
          float v = acc[r] + bv[c];
          vtg[((size_t)b * 256 + c) * 4096 + n] = (ushort_t)cvt_pk_bf16(v, v);
        }
      }
    }
  }
}

// ---------------------------------------------------------------------------
// Flash attention, kv-split-2.  grid 256 = 8 b x 32 q-tiles(128q);
// 512 thr = 8 waves = 4 q-groups(32q) x 2 kv-splits.  Wave: 32 q x 256 ch,
// walks tiles 2i+ks (64 tiles).  Softmax computed once per (q,tile).
// LDS: 4 V bufs (16KB, fragment order) + 4 K bufs (2KB); 4 waves co-stage
// each tile via global_load_lds.  Final (m,l,O) flash-merge through LDS.
// ---------------------------------------------------------------------------
__global__ __launch_bounds__(512, 2) void attn_kernel(
    const ushort_t* __restrict__ qtg, const ushort_t* __restrict__ ktg,
    const ushort_t* __restrict__ vtg, const float* __restrict__ x,
    const float* __restrict__ gamma, float* __restrict__ out)
{
  __shared__ ushort_t vls[4 * 8192];   // 4 x 16KB V tiles, fragment order
  __shared__ ushort_t kls[4 * 1024];   // 4 x  2KB K tiles, fragment order

  const int tid  = threadIdx.x;
  const int lane = tid & 63;
  const int wid  = tid >> 6;           // 0..7
  const int l31  = lane & 31;
  const int half = lane >> 5;
  const int qg   = wid >> 1;           // q-group 0..3
  const int ks   = wid & 1;            // kv-split 0..1
  const int b    = blockIdx.x & 7;     // batch -> XCD pin
  const int qt   = blockIdx.x >> 3;
  const int nq   = qt * 128 + qg * 32 + l31;

  const ushort_t* ktb = ktg + (size_t)b * 4096 * 32;
  const ushort_t* vgb = vtg + (size_t)b * 256 * 4096;

  // persistent Q B-fragments (two o-chunks)
  const ushort_t* qrow = qtg + ((size_t)b * 4096 + nq) * 32;
  const u32x4 q0 = *(const u32x4*)(qrow + half * 8);
  const u32x4 q1 = *(const u32x4*)(qrow + 16 + half * 8);

  // stage tile mt_ into V buffer vb_ / K buffer kb_ (4 waves per tile: qg)
  #define STAGE_PAIR(vb_, kb_, mt_) do {                                      \
    _Pragma("unroll")                                                         \
    for (int jj = 0; jj < 4; ++jj) {                                          \
      const int j  = qg * 4 + jj;                                             \
      const int cc = (j >> 1) * 32 + l31;                                     \
      const int mc = (j & 1) * 2 + half;                                      \
      const ushort_t* gp = vgb + (size_t)cc * 4096 + (mt_) * 32 + mc * 8;     \
      const ushort_t* lp = vls + (vb_) * 8192 + j * 512;                      \
      __builtin_amdgcn_global_load_lds(                                       \
          (const __attribute__((address_space(1))) void*)gp,                  \
          (__attribute__((address_space(3))) void*)lp, 16, 0, 0);             \
    }                                                                         \
    if (qg == 0) {                                                            \
      _Pragma("unroll")                                                       \
      for (int og = 0; og < 2; ++og) {                                        \
        const ushort_t* gp = ktb + (size_t)((mt_) * 32 + l31) * 32 + og * 16 + half * 8; \
        const ushort_t* lp = kls + (kb_) * 1024 + og * 512;                   \
        __builtin_amdgcn_global_load_lds(                                     \
            (const __attribute__((address_space(1))) void*)gp,                \
            (__attribute__((address_space(3))) void*)lp, 16, 0, 0);           \
      }                                                                       \
    }                                                                         \
  } while (0)

  // prologue: stage tiles 0 (ks=0 waves) and 1 (ks=1 waves)
  STAGE_PAIR(ks, ks, ks);
  asm volatile("s_waitcnt vmcnt(0)" ::: "memory");
  __syncthreads();

  float mrun = -3.0e38f, lrun = 0.0f;
  f32x16 oacc[8] = {};

  for (int i = 0; i < 64; ++i) {
    const int pp   = i & 1;
    const int cbuf = pp * 2 + ks;

    if (i < 63) {
      const int nb = (pp ^ 1) * 2 + ks;
      STAGE_PAIR(nb, nb, 2 * i + 2 + ks);
    }

    // K fragments
    const char* kb = (const char*)kls + cbuf * 2048;
    const u32x4 kf0 = *(const u32x4*)(kb + half * 512 + l31 * 16);
    const u32x4 kf1 = *(const u32x4*)(kb + 1024 + half * 512 + l31 * 16);

    // S^T[m][q] = K . Q^T  (32 keys x 32 queries)
    f32x16 s = {};
    __builtin_amdgcn_s_setprio(1);
    s = mfma32(kf0, q0, s);
    s = mfma32(kf1, q1, s);
    __builtin_amdgcn_s_setprio(0);

    // online softmax (lane owns query col; 16 local + 16 partner m-rows)
    float x0 = fmaxf(fmaxf(s[0],  s[1]),  fmaxf(s[2],  s[3]));
    float x1 = fmaxf(fmaxf(s[4],  s[5]),  fmaxf(s[6],  s[7]));
    float x2 = fmaxf(fmaxf(s[8],  s[9]),  fmaxf(s[10], s[11]));
    float x3 = fmaxf(fmaxf(s[12], s[13]), fmaxf(s[14], s[15]));
    const float vmx  = fmaxf(fmaxf(x0, x1), fmaxf(x2, x3));
    const float pmax = cross_half_max(vmx);

    if (__any(pmax > mrun + 8.0f)) {   // defer-max (T13)
      const float mnew = fmaxf(mrun, pmax);
      const float sc   = fast_exp2((mrun - mnew) * L2E);
      lrun *= sc;
      #pragma unroll
      for (int ct = 0; ct < 8; ++ct)
        #pragma unroll
        for (int r = 0; r < 16; ++r) oacc[ct][r] *= sc;
      mrun = mnew;
    }

    const float ml2 = mrun * L2E;
    float p[16];
    #pragma unroll
    for (int r = 0; r < 16; ++r) p[r] = fast_exp2(fmaf(s[r], L2E, -ml2));
    const float ps = (((p[0]+p[1])+(p[2]+p[3])) + ((p[4]+p[5])+(p[6]+p[7])))
                   + (((p[8]+p[9])+(p[10]+p[11])) + ((p[12]+p[13])+(p[14]+p[15])));
    lrun += cross_half_sum(ps);

    // pack to bf16; build PV B-fragments via proven shfl_xor(32) exchange
    const unsigned wd0 = cvt_pk_bf16(p[0],  p[1]),  wd1 = cvt_pk_bf16(p[2],  p[3]);
    const unsigned wd2 = cvt_pk_bf16(p[4],  p[5]),  wd3 = cvt_pk_bf16(p[6],  p[7]);
    const unsigned wd4 = cvt_pk_bf16(p[8],  p[9]),  wd5 = cvt_pk_bf16(p[10], p[11]);
    const unsigned wd6 = cvt_pk_bf16(p[12], p[13]), wd7 = cvt_pk_bf16(p[14], p[15]);
    const unsigned pw0 = __shfl_xor((int)wd0, 32, 64), pw1 = __shfl_xor((int)wd1, 32, 64);
    const unsigned pw2 = __shfl_xor((int)wd2, 32, 64), pw3 = __shfl_xor((int)wd3, 32, 64);
    const unsigned pw4 = __shfl_xor((int)wd4, 32, 64), pw5 = __shfl_xor((int)wd5, 32, 64);
    const unsigned pw6 = __shfl_xor((int)wd6, 32, 64), pw7 = __shfl_xor((int)wd7, 32, 64);
    u32x4 pb0, pb1;
    pb0.x = half ? pw2 : wd0;  pb0.y = half ? pw3 : wd1;
    pb0.z = half ? wd2 : pw0;  pb0.w = half ? wd3 : pw1;
    pb1.x = half ? pw6 : wd4;  pb1.y = half ? pw7 : wd5;
    pb1.z = half ? wd6 : pw4;  pb1.w = half ? wd7 : pw5;

    // O[c][q] += V[c][m] P^T[m][q]  (full 256 channels)
    const char* vb = (const char*)vls + cbuf * 16384;
    __builtin_amdgcn_s_setprio(1);
    #pragma unroll
    for (int ct = 0; ct < 8; ++ct) {
      u32x4 va = *(const u32x4*)(vb + ct * 2048 +        half * 512 + l31 * 16);
      u32x4 vc = *(const u32x4*)(vb + ct * 2048 + 1024 + half * 512 + l31 * 16);
      oacc[ct] = mfma32(va, pb0, oacc[ct]);
      oacc[ct] = mfma32(vc, pb1, oacc[ct]);
    }
    __builtin_amdgcn_s_setprio(0);

    asm volatile("s_waitcnt vmcnt(0)" ::: "memory");
    __syncthreads();
  }

  // ---- flash merge across ks pairs (wid ^ 1), then out = x + g*O/l ----
  float* mf = (float*)kls;             // 8KB region, loop done with it
  mf[wid * 64 + lane]       = mrun;
  mf[512 + wid * 64 + lane] = lrun;
  __syncthreads();
  const float mO = mf[(wid ^ 1) * 64 + lane];
  const float lO = mf[512 + (wid ^ 1) * 64 + lane];
  const float mS    = fmaxf(mrun, mO);
  const float aSelf = fast_exp2((mrun - mS) * L2E);
  const float aOth  = fast_exp2((mO   - mS) * L2E);
  const float linv  = 1.0f / (aSelf * lrun + aOth * lO);
  const float g = gamma[0];
  float* olds = (float*)vls;           // 64KB = 4qg x 4ct x 16r x 64lane f32
  const size_t base = (size_t)b * 256 * 4096 + nq;

  #pragma unroll
  for (int pass = 0; pass < 2; ++pass) {
    const int wks = pass == 0 ? 1 : 0;   // writer kv-split this pass
    if (ks == wks) {
      #pragma unroll
      for (int c4 = 0; c4 < 4; ++c4) {
        const int ct = pass * 4 + c4;
        #pragma unroll
        for (int r = 0; r < 16; ++r)
          olds[((qg * 4 + c4) * 16 + r) * 64 + lane] = aSelf * oacc[ct][r];
      }
    }
    __syncthreads();
    if (ks != wks) {
      #pragma unroll
      for (int c4 = 0; c4 < 4; ++c4) {
        const int ct = pass * 4 + c4;
        #pragma unroll
        for (int r = 0; r < 16; ++r) {
          const float oS = aSelf * oacc[ct][r] +
                           olds[((qg * 4 + c4) * 16 + r) * 64 + lane];
          const int c = ct * 32 + (r & 3) + 8 * (r >> 2) + 4 * half;
          const size_t off = (size_t)c * 4096;
          out[base + off] = x[base + off] + g * (oS * linv);
        }
      }
    }
    if (pass == 0) __syncthreads();
  }
}

extern "C" void kernel_launch(void* const* d_in, const int* in_sizes, int n_in,
                              void* d_out, int out_size, void* d_ws, size_t ws_size,
                              hipStream_t stream) {
  (void)in_sizes; (void)n_in; (void)out_size; (void)ws_size;
  const float* x     = (const float*)d_in[0];
  const float* wq    = (const float*)d_in[1];
  const float* bq    = (const float*)d_in[2];
  const float* wk    = (const float*)d_in[3];
  const float* bk    = (const float*)d_in[4];
  const float* wv    = (const float*)d_in[5];
  const float* bv    = (const float*)d_in[6];
  const float* gamma = (const float*)d_in[7];
  float* out = (float*)d_out;

  ushort_t* ws  = (ushort_t*)d_ws;
  ushort_t* qtw = ws;                              // [8][4096][32] bf16
  ushort_t* ktw = ws + (size_t)8*4096*32;          // [8][4096][32] bf16
  ushort_t* vww = ws + (size_t)2*8*4096*32;        // [8][256][4096] bf16

  proj_kernel<<<1024, 256, 0, stream>>>(x, wq, bq, wk, bk, wv, bv, qtw, ktw, vww);
  attn_kernel<<<256, 512, 0, stream>>>(qtw, ktw, vww, x, gamma, out);
}